// Round 7
// baseline (997.156 us; speedup 1.0000x reference)
//
#include <hip/hip_runtime.h>
#include <math.h>
#include <stdint.h>

#define Bn 512
#define Tn 1024
#define Nn 64
#define LOG2E_F 1.44269504088896340736f
#define LN2_F   0.69314718055994530942f

typedef float v4f __attribute__((ext_vector_type(4)));
typedef short v8s __attribute__((ext_vector_type(8)));

union Frag { uint32_t u[4]; v8s s; };

__device__ __forceinline__ float wave_sum(float v) {
    #pragma unroll
    for (int o = 32; o > 0; o >>= 1) v += __shfl_xor(v, o);
    return v;
}

// pack two f32 -> (bf16(lo) | bf16(hi)<<16) by truncation: one v_perm_b32
__device__ __forceinline__ uint32_t pk_bf16_trunc(float lo, float hi) {
    return __builtin_amdgcn_perm(__float_as_uint(hi), __float_as_uint(lo), 0x07060302u);
}
__device__ __forceinline__ uint32_t f32_bf16_rne(float f) {
    uint32_t u = __float_as_uint(f);
    u += 0x7FFFu + ((u >> 16) & 1u);
    return u >> 16;
}

// ---------------------------------------------------------------------------
// Kernel 1: unary + binary scores -> out[b]
// ---------------------------------------------------------------------------
__global__ __launch_bounds__(256) void crf_scores(
    const float* __restrict__ inputs, const float* __restrict__ trans,
    const int* __restrict__ tags, const int* __restrict__ lens,
    float* __restrict__ out)
{
    const int b = blockIdx.x;
    const int L = lens[b];
    const int* tagb = tags + b * Tn;
    const float* inb = inputs + (size_t)b * Tn * Nn;

    float acc = 0.f;
    for (int t = threadIdx.x; t < L; t += 256) {
        int tg = tagb[t];
        acc += inb[t * Nn + tg];
        if (t >= 1) acc += trans[tagb[t - 1] * Nn + tg];
    }
    acc = wave_sum(acc);
    __shared__ float red[4];
    if ((threadIdx.x & 63) == 0) red[threadIdx.x >> 6] = acc;
    __syncthreads();
    if (threadIdx.x == 0) out[b] = (red[0] + red[1]) + (red[2] + red[3]);
}

// ---------------------------------------------------------------------------
// Kernel 2: MFMA-batched linear recursion in exp-space, 16 chains per wave.
//   fwd: Q(k) = ex(k) (.) (Q(k-1) x E)          E = exp(trans)
//   bwd: G(k) = (ex(t) (.) G(k-1)) x E^T        (row-GEMM form)
// One 64-thread block per 16 batches per direction: 64 blocks total, so at
// most one wave per CU (no DS-pipe contention - that killed R6 at 4 waves/CU).
// Per step: 8 mfma_f32_16x16x32_bf16 + LDS transpose round trip + repack.
// A/B share the k-index convention so any k-permutation cancels; only the
// C layout (col=lane&15, row=quad*4+reg, HW-verified) and m/n lane maps matter.
// ---------------------------------------------------------------------------
template <bool BWD>
__device__ __forceinline__ void chain_body(
    const float* __restrict__ inputs, const float* __restrict__ trans,
    const int* __restrict__ lens, float* __restrict__ ws,
    float* lds, int blk)
{
    const int lane = threadIdx.x;
    const int l = lane & 15, qd = lane >> 4;
    const int bA = blk * 16 + l;                 // this lane's batch (A/pack phase)

    const int L  = lens[bA];
    const int tf = L >> 1;
    const int nb = BWD ? (L - 1 - tf) : tf;      // this batch's step count

    int nmax = nb;
    #pragma unroll
    for (int o = 1; o < 16; o <<= 1) nmax = max(nmax, __shfl_xor(nmax, o));
    nmax = __builtin_amdgcn_readfirstlane(nmax);

    const float* inb = inputs + (size_t)bA * Tn * Nn;

    // B fragments: fwd B=E (B[k][n]=E[k][n]); bwd B=E^T (B[k][n]=E[n][k]).
    // lane holds n=l+16T, k=32c+8qd+j. RNE-rounded bf16 (setup only).
    Frag Bf[4][2];
    #pragma unroll
    for (int T = 0; T < 4; ++T)
        #pragma unroll
        for (int c = 0; c < 2; ++c)
            #pragma unroll
            for (int r = 0; r < 4; ++r) {
                int k0 = 32 * c + 8 * qd + 2 * r;
                int n_ = l + 16 * T;
                float e0, e1;
                if (!BWD) {
                    e0 = exp2f(trans[k0 * 64 + n_] * LOG2E_F);
                    e1 = exp2f(trans[(k0 + 1) * 64 + n_] * LOG2E_F);
                } else {
                    e0 = exp2f(trans[n_ * 64 + k0] * LOG2E_F);
                    e1 = exp2f(trans[n_ * 64 + k0 + 1] * LOG2E_F);
                }
                Bf[T][c].u[r] = f32_bf16_rne(e0) | (f32_bf16_rne(e1) << 16);
            }

    // x row loader: lane's batch, A-layout (states 8qd+j, +32), as 4x float4
    auto load_x = [&](int k, v4f* dst) {
        int t = BWD ? (L - 1 - k) : k;
        t = t < 0 ? 0 : t;                       // dead-lane clamp
        const float* p = inb + t * 64 + 8 * qd;
        dst[0] = *(const v4f*)(p);
        dst[1] = *(const v4f*)(p + 4);
        dst[2] = *(const v4f*)(p + 32);
        dst[3] = *(const v4f*)(p + 36);
    };

    float* vec  = (BWD ? ws + Bn * 64 : ws) + (size_t)bA * 64 + 8 * qd;
    float* bptr = BWD ? (ws + 2 * Bn * 64 + Bn) : (ws + 2 * Bn * 64);

    float base = 0.f;
    Frag Af[2];

    // ---- init A(0): fwd q0 = e^{x0}; bwd h0 = e^{x(L-1)}/64 ----
    {
        v4f x0[4]; load_x(0, x0);
        v4f q0[4];
        #pragma unroll
        for (int i = 0; i < 4; ++i)
            #pragma unroll
            for (int e = 0; e < 4; ++e)
                q0[i][e] = BWD ? exp2f(fmaf(x0[i][e], LOG2E_F, -6.0f))
                               : exp2f(x0[i][e] * LOG2E_F);
        if (nb == 0) {
            if (!BWD) {
                *(v4f*)(vec)      = q0[0]; *(v4f*)(vec + 4)  = q0[1];
                *(v4f*)(vec + 32) = q0[2]; *(v4f*)(vec + 36) = q0[3];
            } else {
                v4f one = {1.f, 1.f, 1.f, 1.f};
                *(v4f*)(vec)      = one; *(v4f*)(vec + 4)  = one;
                *(v4f*)(vec + 32) = one; *(v4f*)(vec + 36) = one;
            }
            if (qd == 0) bptr[bA] = 0.f;
        }
        #pragma unroll
        for (int c = 0; c < 2; ++c)
            #pragma unroll
            for (int r = 0; r < 4; ++r) {
                int j0 = 2 * r;
                float lo = q0[c * 2 + (j0 >> 2)][j0 & 3];
                float hi = q0[c * 2 + ((j0 + 1) >> 2)][(j0 + 1) & 3];
                Af[c].u[r] = pk_bf16_trunc(lo, hi);
            }
    }

    // ---- 2-deep x prefetch ----
    v4f xb[2][4];
    if (nmax >= 1) load_x(1, xb[1]);
    if (nmax >= 2) load_x(2, xb[0]);

    for (int k = 1; k <= nmax; ++k) {
        // ex for this step (loaded 2 iters ago -> off critical path)
        v4f exi[4];
        #pragma unroll
        for (int i = 0; i < 4; ++i)
            #pragma unroll
            for (int e = 0; e < 4; ++e)
                exi[i][e] = exp2f(fmaf(xb[k & 1][i][e], LOG2E_F, -6.0f));
        if (k + 2 <= nmax) load_x(k + 2, xb[k & 1]);

        // 8 MFMAs: C(16x64) = A x B, 4 col-tiles x 2 K-chunks
        v4f acc[4];
        #pragma unroll
        for (int T = 0; T < 4; ++T) {
            v4f z = {0.f, 0.f, 0.f, 0.f};
            z = __builtin_amdgcn_mfma_f32_16x16x32_bf16(Af[0].s, Bf[T][0].s, z, 0, 0, 0);
            z = __builtin_amdgcn_mfma_f32_16x16x32_bf16(Af[1].s, Bf[T][1].s, z, 0, 0, 0);
            acc[T] = z;
        }

        // C -> LDS [b][s], stride 68 (C layout: row b=4qd+r, col s=l+16T)
        #pragma unroll
        for (int T = 0; T < 4; ++T)
            #pragma unroll
            for (int r = 0; r < 4; ++r)
                lds[(4 * qd + r) * 68 + l + 16 * T] = acc[T][r];

        __builtin_amdgcn_wave_barrier();
        asm volatile("" ::: "memory");           // in-order DS pipe, 1 wave: RAW-safe

        // LDS -> A-layout (lane's batch row l, states 8qd+j, +32): 4x b128
        v4f qv[4];
        {
            const float* p = &lds[l * 68 + 8 * qd];
            qv[0] = *(const v4f*)(p);
            qv[1] = *(const v4f*)(p + 4);
            qv[2] = *(const v4f*)(p + 32);
            qv[3] = *(const v4f*)(p + 36);
        }

        v4f qq[4];
        if (!BWD) {
            #pragma unroll
            for (int i = 0; i < 4; ++i) qq[i] = qv[i] * exi[i];
            if (k == nb) {                       // snapshot f = Q(tf)
                *(v4f*)(vec)      = qq[0]; *(v4f*)(vec + 4)  = qq[1];
                *(v4f*)(vec + 32) = qq[2]; *(v4f*)(vec + 36) = qq[3];
                if (qd == 0) bptr[bA] = base + 6.0f * LN2_F * (float)nb;
            }
        } else {
            if (k == nb) {                       // snapshot g = G(tf+1), pre-ex
                *(v4f*)(vec)      = qv[0]; *(v4f*)(vec + 4)  = qv[1];
                *(v4f*)(vec + 32) = qv[2]; *(v4f*)(vec + 36) = qv[3];
                if (qd == 0) bptr[bA] = base + 6.0f * LN2_F * (float)nb;
            }
            #pragma unroll
            for (int i = 0; i < 4; ++i) qq[i] = qv[i] * exi[i];
        }

        if ((k & 7) == 0) {                      // per-batch renorm (range safety)
            float m = qq[0][0];
            #pragma unroll
            for (int i = 0; i < 4; ++i)
                #pragma unroll
                for (int e = 0; e < 4; ++e) m = fmaxf(m, qq[i][e]);
            m = fmaxf(m, __shfl_xor(m, 16));
            m = fmaxf(m, __shfl_xor(m, 32));
            float inv = 1.0f / m;
            #pragma unroll
            for (int i = 0; i < 4; ++i) qq[i] = qq[i] * inv;
            base += __logf(m);
        }

        // repack A (bf16 truncation via v_perm)
        #pragma unroll
        for (int c = 0; c < 2; ++c)
            #pragma unroll
            for (int r = 0; r < 4; ++r) {
                int j0 = 2 * r;
                float lo = qq[c * 2 + (j0 >> 2)][j0 & 3];
                float hi = qq[c * 2 + ((j0 + 1) >> 2)][(j0 + 1) & 3];
                Af[c].u[r] = pk_bf16_trunc(lo, hi);
            }
    }
}

__global__ __launch_bounds__(64, 1) void crf_chain(
    const float* __restrict__ inputs, const float* __restrict__ trans,
    const int* __restrict__ lens, float* __restrict__ ws)
{
    __shared__ float lds[16 * 68 + 4];
    if (blockIdx.x < Bn / 16)
        chain_body<false>(inputs, trans, lens, ws, lds, blockIdx.x);
    else
        chain_body<true>(inputs, trans, lens, ws, lds, blockIdx.x - Bn / 16);
}

// ---------------------------------------------------------------------------
// Kernel 3: combine halves: logZ = log(f . g) + fbase + gbase; out[b] -= logZ
// ---------------------------------------------------------------------------
__global__ __launch_bounds__(64, 1) void crf_combine(
    const float* __restrict__ ws, float* __restrict__ out)
{
    const int b = blockIdx.x;
    const int j = threadIdx.x;
    const float* fvec = ws;
    const float* gvec = ws + Bn * 64;
    const float* fb   = ws + 2 * Bn * 64;
    const float* gb   = fb + Bn;

    float p = wave_sum(fvec[b * 64 + j] * gvec[b * 64 + j]);
    if (j == 0) out[b] -= (__logf(p) + fb[b] + gb[b]);
}

extern "C" void kernel_launch(void* const* d_in, const int* in_sizes, int n_in,
                              void* d_out, int out_size, void* d_ws, size_t ws_size,
                              hipStream_t stream) {
    const float* inputs = (const float*)d_in[0];
    const float* trans  = (const float*)d_in[1];
    const int*   tags   = (const int*)d_in[2];
    const int*   lens   = (const int*)d_in[3];
    float* out = (float*)d_out;
    float* ws  = (float*)d_ws;

    crf_scores<<<Bn, 256, 0, stream>>>(inputs, trans, tags, lens, out);
    crf_chain<<<2 * (Bn / 16), 64, 0, stream>>>(inputs, trans, lens, ws);
    crf_combine<<<Bn, 64, 0, stream>>>(ws, out);
}